// Round 7
// baseline (3575.331 us; speedup 1.0000x reference)
//
#include <hip/hip_runtime.h>
#include <cstddef>

namespace {

typedef _Float16 half_t;
typedef _Float16 f16x4 __attribute__((ext_vector_type(4)));
typedef _Float16 f16x8 __attribute__((ext_vector_type(8)));
typedef float f32x4 __attribute__((ext_vector_type(4)));

constexpr int NB = 256;  // batch
constexpr int NT = 512;  // time
constexpr int NH = 128;  // hidden
constexpr int NG = 512;  // 4*NH gates

__device__ __forceinline__ float sigm(float x) { return 1.0f / (1.0f + __expf(-x)); }
__device__ __forceinline__ float tanh_(float x) { return 2.0f / (1.0f + __expf(-2.0f * x)) - 1.0f; }
__device__ __forceinline__ void pinv8(f16x8& x) { asm volatile("" : "+v"(x)); }

// xg fragment-layout offset (halfs): [t][bblk][w][fn][u][row]
__device__ __forceinline__ size_t xg_off(int t, int bblk, int w, int fn, int u, int row) {
  return ((size_t)((t * 16 + bblk) * 8 + w)) * 1024 + (size_t)((fn * 16 + u) * 16 + row);
}

// fp32 -> fp16 conversion (Whh prep)
__global__ void cvt_kernel(const float* __restrict__ s, half_t* __restrict__ d, int n4) {
  int i = blockIdx.x * blockDim.x + threadIdx.x;
  if (i < n4) {
    float4 v = reinterpret_cast<const float4*>(s)[i];
    f16x4 hv = {(half_t)v.x, (half_t)v.y, (half_t)v.z, (half_t)v.w};
    reinterpret_cast<f16x4*>(d)[i] = hv;
  }
}

// ============ MFMA GEMM ============
// C[M=131072, N tile] = A[M,K] * B[N,K]^T (+ biases).  BM=128, BN=64, 4 waves.
// AMAP 0: A fp16, rows = m (seqA time-major [t*NB+b][K])
// AMAP 1: A fp32 from x[b][t][K] with t = m>>8 (const per tile), b = (m&255)+row
// OUT  0: frag-layout fp16 xg (+b0+b1), packed 4-row (q) 8-B stores
// OUT  2: projection fp32: out[b][t][n] = acc + b0[n]
template <int K, int AMAP, int OUT>
__global__ __launch_bounds__(256) void xg_gemm(
    const void* __restrict__ Ap, const float* __restrict__ Bw,
    const float* __restrict__ b0, const float* __restrict__ b1,
    half_t* __restrict__ Co, float* __restrict__ Cf)
{
  __shared__ __align__(16) half_t Atile[128 * K];
  __shared__ __align__(16) half_t Btile[64 * K];
  const int tid = threadIdx.x;
  const int m0 = blockIdx.x * 128;
  const int n0 = blockIdx.y * 64;
  char* Ab = (char*)Atile;
  char* Bb = (char*)Btile;

  if (AMAP == 1) {
    const float* Af = (const float*)Ap;
    const int t_fix = m0 >> 8, b_base = m0 & 255;
    for (int idx = tid; idx < 128 * K / 4; idx += 256) {
      int row = idx / (K / 4), o = idx % (K / 4);
      float4 v = *(const float4*)(Af + ((size_t)(b_base + row) * NT + t_fix) * K + 4 * o);
      f16x4 hv = {(half_t)v.x, (half_t)v.y, (half_t)v.z, (half_t)v.w};
      int byte = ((row * K + 4 * o) * 2) ^ ((row & 7) << 4);
      *(f16x4*)(Ab + byte) = hv;
    }
  } else {
    const half_t* Ah = (const half_t*)Ap;
    for (int idx = tid; idx < 128 * K / 8; idx += 256) {
      int row = idx / (K / 8), o = idx % (K / 8);
      uint4 v = *(const uint4*)(Ah + (size_t)(m0 + row) * K + 8 * o);
      int byte = ((row * K + 8 * o) * 2) ^ ((row & 7) << 4);
      *(uint4*)(Ab + byte) = v;
    }
  }
  for (int idx = tid; idx < 64 * K / 4; idx += 256) {
    int row = idx / (K / 4), o = idx % (K / 4);
    float4 v = *(const float4*)(Bw + (size_t)(n0 + row) * K + 4 * o);
    f16x4 hv = {(half_t)v.x, (half_t)v.y, (half_t)v.z, (half_t)v.w};
    int byte = ((row * K + 4 * o) * 2) ^ ((row & 7) << 4);
    *(f16x4*)(Bb + byte) = hv;
  }
  __syncthreads();

  const int lane = tid & 63, wv = tid >> 6;
  const int r16 = lane & 15, g4 = lane >> 4, koff = g4 * 8;
  f32x4 acc[2][4];
#pragma unroll
  for (int fm = 0; fm < 2; ++fm)
#pragma unroll
    for (int fn = 0; fn < 4; ++fn) acc[fm][fn] = (f32x4){0.f, 0.f, 0.f, 0.f};

#pragma unroll
  for (int ks = 0; ks < K / 32; ++ks) {
    f16x8 a[2], bf[4];
#pragma unroll
    for (int fm = 0; fm < 2; ++fm) {
      int row = wv * 32 + fm * 16 + r16;
      int byte = ((row * K + ks * 32 + koff) * 2) ^ ((row & 7) << 4);
      a[fm] = *(const f16x8*)(Ab + byte);
    }
#pragma unroll
    for (int fn = 0; fn < 4; ++fn) {
      int row = fn * 16 + r16;
      int byte = ((row * K + ks * 32 + koff) * 2) ^ ((row & 7) << 4);
      bf[fn] = *(const f16x8*)(Bb + byte);
    }
#pragma unroll
    for (int fm = 0; fm < 2; ++fm)
#pragma unroll
      for (int fn = 0; fn < 4; ++fn)
        acc[fm][fn] = __builtin_amdgcn_mfma_f32_16x16x32_f16(a[fm], bf[fn], acc[fm][fn], 0, 0, 0);
  }

  // D layout: col = lane&15 (n), row = g4*4 + q (m)
  if (OUT == 0) {
    const int t = m0 >> 8;
#pragma unroll
    for (int fm = 0; fm < 2; ++fm)
#pragma unroll
      for (int fn = 0; fn < 4; ++fn) {
        const int gate = n0 + fn * 16 + r16;
        const float bb = b0[gate] + b1[gate];
        const int b_lo = (m0 & 255) + wv * 32 + fm * 16 + g4 * 4;  // + q (q<4, no 16-cross)
        const int bblk = b_lo >> 4, row = b_lo & 15;
        const int fnG = gate >> 7, w2 = (gate & 127) >> 4;
        const size_t off =
            ((size_t)(t * 16 + bblk) * 8 + w2) * 1024 + (size_t)((fnG * 16 + r16) * 16 + row);
        f16x4 pk = {(half_t)(acc[fm][fn][0] + bb), (half_t)(acc[fm][fn][1] + bb),
                    (half_t)(acc[fm][fn][2] + bb), (half_t)(acc[fm][fn][3] + bb)};
        *(f16x4*)(Co + off) = pk;
      }
  } else {
    const int t = m0 >> 8;
#pragma unroll
    for (int fm = 0; fm < 2; ++fm)
#pragma unroll
      for (int fn = 0; fn < 4; ++fn) {
        const int n = n0 + fn * 16 + r16;
        const float bb = b0[n];
#pragma unroll
        for (int q = 0; q < 4; ++q) {
          const int b = (m0 & 255) + wv * 32 + fm * 16 + g4 * 4 + q;
          Cf[((size_t)b * NT + t) * 64 + n] = acc[fm][fn][q] + bb;
        }
      }
  }
}

// ============ MFMA recurrence ============
// 16 blocks (16 batch each) x 512 threads (8 waves). Wave w owns units
// w*16..w*16+15, all 4 gates: B-frags = Whh rows {fn*128 + w*16 + u}, resident
// in 64 VGPRs. Per step: 4 ds_read_b128 (h A-frags) + 16 MFMA + in-lane gates
// (i,f,g,o of a unit are acc[0..3] in the same lane; c[4] in registers; no
// shuffles) + 4 ds_write_b16. xg streamed from frag-layout buffer, prefetch
// depth 2, used as MFMA C-init. h kept in an 8-slot LDS ring (row pad 136
// halfs); seq output dumped coalesced every 8 steps (time-major).
// MODE: 0 = seq-out; 1 = hT-out only; 2 = const xg from hT_in (dec0), seq-out
template <int MODE>
__global__ __attribute__((amdgpu_flat_work_group_size(512, 512)))
__attribute__((amdgpu_waves_per_eu(2, 2))) void rec_mfma(
    const half_t* __restrict__ xgF,
    const float* __restrict__ hT_in, const float* __restrict__ Wih32,
    const float* __restrict__ bih, const float* __restrict__ bhh,
    const half_t* __restrict__ Whh,
    half_t* __restrict__ seq_out,   // [NT][NB][NH] fp16 time-major
    float* __restrict__ hT_out)     // [NB][NH]
{
  const int tid = threadIdx.x;
  const int w = tid >> 6, lane = tid & 63;
  const int u = lane & 15, g4 = lane >> 4;
  const int bblk = blockIdx.x, b0 = bblk * 16;

  __shared__ __align__(16) half_t hist[8][16][136];

  // Resident B-frags: wh[fn][ks] lane holds Whh[fn*128+w*16+u][ks*32+g4*8 ..+8]
  f16x8 wh[4][4];
#pragma unroll
  for (int fn = 0; fn < 4; ++fn)
#pragma unroll
    for (int ks = 0; ks < 4; ++ks)
      wh[fn][ks] =
          *(const f16x8*)(Whh + (size_t)(fn * 128 + w * 16 + u) * NH + ks * 32 + g4 * 8);
#pragma unroll
  for (int fn = 0; fn < 4; ++fn)
#pragma unroll
    for (int ks = 0; ks < 4; ++ks) pinv8(wh[fn][ks]);

  {  // h0 = 0 into slot 7 (read at t=0)
    int m = tid >> 5, k0 = (tid & 31) * 4;
    f16x4 z = {(half_t)0.f, (half_t)0.f, (half_t)0.f, (half_t)0.f};
    *(f16x4*)&hist[7][m][k0] = z;
  }

  float c[4] = {0.f, 0.f, 0.f, 0.f};

  f32x4 accC[4];
  if (MODE == 2) {
    // one-time const xg = hT . Wih^T + biases, via MFMA (frag-native)
    f16x8 ah[4];
#pragma unroll
    for (int ks = 0; ks < 4; ++ks) {
      const float* hp = hT_in + (size_t)(b0 + u) * NH + ks * 32 + g4 * 8;
      float4 v0 = *(const float4*)hp, v1 = *(const float4*)(hp + 4);
      f16x8 t8;
      t8[0] = (half_t)v0.x; t8[1] = (half_t)v0.y; t8[2] = (half_t)v0.z; t8[3] = (half_t)v0.w;
      t8[4] = (half_t)v1.x; t8[5] = (half_t)v1.y; t8[6] = (half_t)v1.z; t8[7] = (half_t)v1.w;
      ah[ks] = t8;
    }
#pragma unroll
    for (int fn = 0; fn < 4; ++fn) {
      const int gate = fn * 128 + w * 16 + u;
      f32x4 a = {0.f, 0.f, 0.f, 0.f};
#pragma unroll
      for (int ks = 0; ks < 4; ++ks) {
        const float* wp = Wih32 + (size_t)gate * NH + ks * 32 + g4 * 8;
        float4 v0 = *(const float4*)wp, v1 = *(const float4*)(wp + 4);
        f16x8 t8;
        t8[0] = (half_t)v0.x; t8[1] = (half_t)v0.y; t8[2] = (half_t)v0.z; t8[3] = (half_t)v0.w;
        t8[4] = (half_t)v1.x; t8[5] = (half_t)v1.y; t8[6] = (half_t)v1.z; t8[7] = (half_t)v1.w;
        a = __builtin_amdgcn_mfma_f32_16x16x32_f16(ah[ks], t8, a, 0, 0, 0);
      }
      const float bs = bih[gate] + bhh[gate];
      a[0] += bs; a[1] += bs; a[2] += bs; a[3] += bs;
      accC[fn] = a;
    }
  }

  // xg prefetch (depth 2), separate named arrays (no runtime indexing)
  f16x4 st0[4], st1[4];
  if (MODE != 2) {
#pragma unroll
    for (int fn = 0; fn < 4; ++fn) {
      st0[fn] = *(const f16x4*)(xgF + xg_off(0, bblk, w, fn, u, g4 * 4));
      st1[fn] = *(const f16x4*)(xgF + xg_off(1, bblk, w, fn, u, g4 * 4));
    }
  }

  __syncthreads();

  auto step = [&](int t, f16x4 (&st)[4]) {
    const int rd = (t + 7) & 7, wr = t & 7;

    f32x4 acc[4];
    if (MODE == 2) {
#pragma unroll
      for (int fn = 0; fn < 4; ++fn) acc[fn] = accC[fn];
    } else {
#pragma unroll
      for (int fn = 0; fn < 4; ++fn) {
        f16x4 s = st[fn];
        acc[fn] = (f32x4){(float)s[0], (float)s[1], (float)s[2], (float)s[3]};
      }
      if (t + 2 < NT) {
#pragma unroll
        for (int fn = 0; fn < 4; ++fn)
          st[fn] = *(const f16x4*)(xgF + xg_off(t + 2, bblk, w, fn, u, g4 * 4));
      }
    }

    f16x8 a[4];
#pragma unroll
    for (int ks = 0; ks < 4; ++ks)
      a[ks] = *(const f16x8*)&hist[rd][u][ks * 32 + g4 * 8];
#pragma unroll
    for (int fn = 0; fn < 4; ++fn)
#pragma unroll
      for (int ks = 0; ks < 4; ++ks)
        acc[fn] = __builtin_amdgcn_mfma_f32_16x16x32_f16(a[ks], wh[fn][ks], acc[fn], 0, 0, 0);

#pragma unroll
    for (int q = 0; q < 4; ++q) {
      const float ig = sigm(acc[0][q]);
      const float fg = sigm(acc[1][q]);
      const float gg = tanh_(acc[2][q]);
      const float og = sigm(acc[3][q]);
      c[q] = fmaf(fg, c[q], ig * gg);
      const float h = og * tanh_(c[q]);
      hist[wr][g4 * 4 + q][w * 16 + u] = (half_t)h;
      if (MODE == 1 && t == NT - 1)
        hT_out[(size_t)(b0 + g4 * 4 + q) * NH + w * 16 + u] = h;
    }
    __syncthreads();

    if (MODE != 1 && wr == 7) {
      // coalesced dump of 8 steps: 128 rows x 256 B; 4 threads/row x 64 B
      const int r = tid >> 2, s = r >> 4, m = r & 15, cc = (tid & 3) * 32;
      const size_t grow = ((size_t)(t - 7 + s) * NB + b0 + m) * NH + cc;
#pragma unroll
      for (int i = 0; i < 4; ++i)
        *(uint4*)(seq_out + grow + i * 8) = *(const uint4*)&hist[s][m][cc + i * 8];
      __syncthreads();  // dump reads complete before next chunk overwrites slots
    }
  };

  for (int t2 = 0; t2 < NT; t2 += 2) {  // 2-step unroll keeps st0/st1 static (rule #20)
    step(t2, st0);
    step(t2 + 1, st1);
  }
}

}  // namespace

extern "C" void kernel_launch(void* const* d_in, const int* in_sizes, int n_in,
                              void* d_out, int out_size, void* d_ws, size_t ws_size,
                              hipStream_t stream) {
  (void)in_sizes; (void)n_in; (void)out_size; (void)ws_size;

  const float* x     = (const float*)d_in[0];
  const float* e0Wih = (const float*)d_in[1];
  const float* e0Whh = (const float*)d_in[2];
  const float* e0bih = (const float*)d_in[3];
  const float* e0bhh = (const float*)d_in[4];
  const float* e1Wih = (const float*)d_in[5];
  const float* e1Whh = (const float*)d_in[6];
  const float* e1bih = (const float*)d_in[7];
  const float* e1bhh = (const float*)d_in[8];
  const float* d0Wih = (const float*)d_in[9];
  const float* d0Whh = (const float*)d_in[10];
  const float* d0bih = (const float*)d_in[11];
  const float* d0bhh = (const float*)d_in[12];
  const float* d1Wih = (const float*)d_in[13];
  const float* d1Whh = (const float*)d_in[14];
  const float* d1bih = (const float*)d_in[15];
  const float* d1bhh = (const float*)d_in[16];
  const float* Wout  = (const float*)d_in[17];
  const float* bout  = (const float*)d_in[18];
  float* out = (float*)d_out;

  // ws: Whh fp16 x4 | seqA fp16 [NT*NB*NH] time-major | xgF fp16 frag | hT f32
  half_t* whh0 = (half_t*)d_ws;
  half_t* whh1 = whh0 + 512 * 128;
  half_t* whh2 = whh1 + 512 * 128;
  half_t* whh3 = whh2 + 512 * 128;
  half_t* seqA = whh3 + 512 * 128;
  half_t* xgF  = seqA + (size_t)NT * NB * NH;
  float*  hT   = (float*)(xgF + (size_t)NT * NB * NG);

  cvt_kernel<<<64, 256, 0, stream>>>(e0Whh, whh0, 512 * 128 / 4);
  cvt_kernel<<<64, 256, 0, stream>>>(e1Whh, whh1, 512 * 128 / 4);
  cvt_kernel<<<64, 256, 0, stream>>>(d0Whh, whh2, 512 * 128 / 4);
  cvt_kernel<<<64, 256, 0, stream>>>(d1Whh, whh3, 512 * 128 / 4);

  dim3 blkG(256), gX(NB * NT / 128, NG / 64), gP(NB * NT / 128, 1);
  dim3 gR(16), blkR(512);

  // enc0: xg = x @ e0Wih^T + b (A fp32 via transpose-map), rec -> seqA
  xg_gemm<64, 1, 0><<<gX, blkG, 0, stream>>>(x, e0Wih, e0bih, e0bhh, xgF, nullptr);
  rec_mfma<0><<<gR, blkR, 0, stream>>>(xgF, nullptr, nullptr, nullptr, nullptr, whh0,
                                       seqA, nullptr);
  // enc1: xg = seqA @ e1Wih^T + b, rec -> hT
  xg_gemm<128, 0, 0><<<gX, blkG, 0, stream>>>(seqA, e1Wih, e1bih, e1bhh, xgF, nullptr);
  rec_mfma<1><<<gR, blkR, 0, stream>>>(xgF, nullptr, nullptr, nullptr, nullptr, whh1,
                                       nullptr, hT);
  // dec0: const xg from hT (computed in-kernel), rec -> seqA
  rec_mfma<2><<<gR, blkR, 0, stream>>>(nullptr, hT, d0Wih, d0bih, d0bhh, whh2,
                                       seqA, nullptr);
  // dec1: xg = seqA @ d1Wih^T + b, rec -> seqA
  xg_gemm<128, 0, 0><<<gX, blkG, 0, stream>>>(seqA, d1Wih, d1bih, d1bhh, xgF, nullptr);
  rec_mfma<0><<<gR, blkR, 0, stream>>>(xgF, nullptr, nullptr, nullptr, nullptr, whh3,
                                       seqA, nullptr);
  // projection: out[b][t][f] = seqA @ Wout^T + bout
  xg_gemm<128, 0, 2><<<gP, blkG, 0, stream>>>(seqA, Wout, bout, nullptr, nullptr, out);
}

// Round 8
// 3233.769 us; speedup vs baseline: 1.1056x; 1.1056x over previous
//
#include <hip/hip_runtime.h>
#include <cstddef>

namespace {

typedef _Float16 half_t;
typedef _Float16 half2_t __attribute__((ext_vector_type(2)));
typedef _Float16 f16x4 __attribute__((ext_vector_type(4)));
typedef _Float16 f16x8 __attribute__((ext_vector_type(8)));
typedef float f32x4 __attribute__((ext_vector_type(4)));

constexpr int NB = 256;  // batch
constexpr int NT = 512;  // time
constexpr int NH = 128;  // hidden
constexpr int NG = 512;  // 4*NH gates

__device__ __forceinline__ float sigm(float x) { return 1.0f / (1.0f + __expf(-x)); }
__device__ __forceinline__ float tanh_(float x) { return 2.0f / (1.0f + __expf(-2.0f * x)) - 1.0f; }
__device__ __forceinline__ float dot4(float4 w, float4 v, float acc) {
  return fmaf(w.x, v.x, fmaf(w.y, v.y, fmaf(w.z, v.z, fmaf(w.w, v.w, acc))));
}
__device__ __forceinline__ float fdot2(half2_t a, half2_t b, float c) {
  return __builtin_amdgcn_fdot2(a, b, c, false);  // v_dot2_f32_f16, f32 accum
}
__device__ __forceinline__ half2_t lo2(f16x8 v, int q) {  // extract pair q (0..3)
  half2_t r; r[0] = v[2 * q]; r[1] = v[2 * q + 1]; return r;
}
__device__ __forceinline__ void pinv8(f16x8& x) { asm volatile("" : "+v"(x)); }

// fp32 -> fp16 conversion (Whh prep)
__global__ void cvt_kernel(const float* __restrict__ s, half_t* __restrict__ d, int n4) {
  int i = blockIdx.x * blockDim.x + threadIdx.x;
  if (i < n4) {
    float4 v = reinterpret_cast<const float4*>(s)[i];
    f16x4 hv = {(half_t)v.x, (half_t)v.y, (half_t)v.z, (half_t)v.w};
    reinterpret_cast<f16x4*>(d)[i] = hv;
  }
}

// ============ MFMA GEMM: C[M,Nstr tile] = A[M,K] * B[N,K]^T + b0 + b1 ============
// BM=128, BN=64, 256 threads = 4 waves (each wave: 32 rows x 64 cols, 2x4 frags).
template <int K, bool AF32, bool F32OUT>
__global__ __launch_bounds__(256) void xg_gemm(
    const void* __restrict__ Ap, const float* __restrict__ Bw,
    const float* __restrict__ b0, const float* __restrict__ b1,
    half_t* __restrict__ Ch, float* __restrict__ Cf, int Nstr)
{
  __shared__ __align__(16) half_t Atile[128 * K];
  __shared__ __align__(16) half_t Btile[64 * K];
  const int tid = threadIdx.x;
  const int m0 = blockIdx.x * 128;
  const int n0 = blockIdx.y * 64;
  char* Ab = (char*)Atile;
  char* Bb = (char*)Btile;

  if (AF32) {
    const float* Af = (const float*)Ap;
    for (int idx = tid; idx < 128 * K / 4; idx += 256) {
      int row = idx / (K / 4), o = idx % (K / 4);
      float4 v = *(const float4*)(Af + (size_t)(m0 + row) * K + 4 * o);
      f16x4 hv = {(half_t)v.x, (half_t)v.y, (half_t)v.z, (half_t)v.w};
      int byte = ((row * K + 4 * o) * 2) ^ ((row & 7) << 4);
      *(f16x4*)(Ab + byte) = hv;
    }
  } else {
    const half_t* Ah = (const half_t*)Ap;
    for (int idx = tid; idx < 128 * K / 8; idx += 256) {
      int row = idx / (K / 8), o = idx % (K / 8);
      uint4 v = *(const uint4*)(Ah + (size_t)(m0 + row) * K + 8 * o);
      int byte = ((row * K + 8 * o) * 2) ^ ((row & 7) << 4);
      *(uint4*)(Ab + byte) = v;
    }
  }
  for (int idx = tid; idx < 64 * K / 4; idx += 256) {
    int row = idx / (K / 4), o = idx % (K / 4);
    float4 v = *(const float4*)(Bw + (size_t)(n0 + row) * K + 4 * o);
    f16x4 hv = {(half_t)v.x, (half_t)v.y, (half_t)v.z, (half_t)v.w};
    int byte = ((row * K + 4 * o) * 2) ^ ((row & 7) << 4);
    *(f16x4*)(Bb + byte) = hv;
  }
  __syncthreads();

  const int lane = tid & 63, w = tid >> 6;
  const int r16 = lane & 15, koff = (lane >> 4) * 8;
  f32x4 acc[2][4];
#pragma unroll
  for (int fm = 0; fm < 2; ++fm)
#pragma unroll
    for (int fn = 0; fn < 4; ++fn) acc[fm][fn] = (f32x4){0.f, 0.f, 0.f, 0.f};

#pragma unroll
  for (int ks = 0; ks < K / 32; ++ks) {
    f16x8 a[2], bf[4];
#pragma unroll
    for (int fm = 0; fm < 2; ++fm) {
      int row = w * 32 + fm * 16 + r16;
      int byte = ((row * K + ks * 32 + koff) * 2) ^ ((row & 7) << 4);
      a[fm] = *(const f16x8*)(Ab + byte);
    }
#pragma unroll
    for (int fn = 0; fn < 4; ++fn) {
      int row = fn * 16 + r16;
      int byte = ((row * K + ks * 32 + koff) * 2) ^ ((row & 7) << 4);
      bf[fn] = *(const f16x8*)(Bb + byte);
    }
#pragma unroll
    for (int fm = 0; fm < 2; ++fm)
#pragma unroll
      for (int fn = 0; fn < 4; ++fn)
        acc[fm][fn] = __builtin_amdgcn_mfma_f32_16x16x32_f16(a[fm], bf[fn], acc[fm][fn], 0, 0, 0);
  }

  // D layout: col = lane&15, row = (lane>>4)*4 + q
#pragma unroll
  for (int fm = 0; fm < 2; ++fm)
#pragma unroll
    for (int fn = 0; fn < 4; ++fn) {
      int n = n0 + fn * 16 + r16;
      float bb = (b0 ? b0[n] : 0.f) + (b1 ? b1[n] : 0.f);
#pragma unroll
      for (int q = 0; q < 4; ++q) {
        int m = m0 + w * 32 + fm * 16 + (lane >> 4) * 4 + q;
        float val = acc[fm][fn][q] + bb;
        if (F32OUT) Cf[(size_t)m * Nstr + n] = val;
        else        Ch[(size_t)m * Nstr + n] = (half_t)val;
      }
    }
}

// ============ Recurrent kernel: 2 batch elements per 1024-thread block ============
// 128 blocks x 1024 threads (16 waves = 4/SIMD). Each 512-thread half runs one
// batch element with r6's layout (j = t5>>2 hidden unit, kq = t5&3 k-quarter).
// Two independent per-step dependency chains per block + 4 waves/SIMD hide the
// ds_read/shuffle/transcendental latency that bounded r6 at 2310 cyc/step.
// MODE: 0 = xg-stream -> seq-out (enc0, dec1)
//       1 = xg-stream -> hT-out  (enc1)
//       2 = const-xg  -> seq-out (dec0; xg from hT_in, computed once)
template <int MODE>
__global__ __attribute__((amdgpu_flat_work_group_size(1024, 1024)))
__attribute__((amdgpu_waves_per_eu(4, 4))) void rec_kernel(
    const half_t* __restrict__ xg,     // [NB*NT,NG] fp16 (modes 0/1), biases folded
    const float* __restrict__ hT_in,   // [NB,NH]        (mode 2)
    const float* __restrict__ WihD,    // [NG,NH] fp32   (mode 2)
    const float* __restrict__ bih, const float* __restrict__ bhh,  // (mode 2)
    const half_t* __restrict__ Whh,    // [NG,NH] fp16
    half_t* __restrict__ seq_out,      // [NB,NT,NH] fp16 (modes 0/2)
    float* __restrict__ hT_out)        // [NB,NH]         (mode 1)
{
  const int tid = threadIdx.x;
  const int hf = tid >> 9;   // which batch of the pair
  const int t5 = tid & 511;  // thread index within the half
  const int b = blockIdx.x * 2 + hf;
  const int j = t5 >> 2;     // hidden unit [0,128)
  const int kq = t5 & 3;     // k-quarter  [0,4)

  // per-half h double-buffer: quarters padded to 48 halfs (96 B) -> bases on
  // distinct banks; uniform-address broadcast b128 reads, conflict-free.
  __shared__ __align__(16) half_t hbuf[2][2][4][48];   // [half][parity][kq][..]
  __shared__ __align__(16) half_t xgs[2][2][8][NG];    // [half][buf][step][gate]
  __shared__ float xgc[2][NG];                         // const xg (mode 2)
  __shared__ float hinf[2][NH];

  // Resident recurrent weights: 4 gates x 32 k = 16 x f16x8 (64 VGPRs), pinned.
  // Same weights for both halves (same layer).
  f16x8 wh8[4][4];
#pragma unroll
  for (int gi = 0; gi < 4; ++gi) {
    const f16x8* p = reinterpret_cast<const f16x8*>(Whh + (size_t)(gi * NH + j) * NH + kq * 32);
#pragma unroll
    for (int r = 0; r < 4; ++r) wh8[gi][r] = p[r];
  }
#pragma unroll
  for (int gi = 0; gi < 4; ++gi)
#pragma unroll
    for (int r = 0; r < 4; ++r) pinv8(wh8[gi][r]);

  if (t5 < NH) hbuf[hf][0][t5 >> 5][t5 & 31] = (half_t)0.0f;  // h0 = 0
  float c = 0.0f;                                             // c0 (replicated x4 kq lanes)

  if (MODE == 2) {
    // one-time: xgc[g] = bih+bhh + Wih[g,:].hT[b,:]  (fp32, thread = gate)
    if (t5 < NH) hinf[hf][t5] = hT_in[(size_t)b * NH + t5];
    __syncthreads();
    float a0 = bih[t5] + bhh[t5], a1 = 0.f, a2 = 0.f, a3 = 0.f;
    const float4* wr = (const float4*)(WihD + (size_t)t5 * NH);
    const float4* hv = (const float4*)&hinf[hf][0];
#pragma unroll
    for (int k = 0; k < 8; ++k) {
      a0 = dot4(wr[4 * k + 0], hv[4 * k + 0], a0);
      a1 = dot4(wr[4 * k + 1], hv[4 * k + 1], a1);
      a2 = dot4(wr[4 * k + 2], hv[4 * k + 2], a2);
      a3 = dot4(wr[4 * k + 3], hv[4 * k + 3], a3);
    }
    xgc[hf][t5] = (a0 + a1) + (a2 + a3);
    __syncthreads();
  }

  half_t g[8];
  const half_t* xrow = nullptr;
  if (MODE != 2) {
    xrow = xg + (size_t)b * NT * NG + t5;  // thread = gate column of its batch
#pragma unroll
    for (int s = 0; s < 8; ++s) g[s] = xrow[(size_t)s * NG];  // chunk 0
  }

  for (int ch = 0; ch < NT / 8; ++ch) {
    if (MODE != 2) {
      // commit staged chunk to LDS; issue loads for next chunk (hidden under 8 steps)
#pragma unroll
      for (int s = 0; s < 8; ++s) xgs[hf][ch & 1][s][t5] = g[s];
      if (ch < NT / 8 - 1) {
#pragma unroll
        for (int s = 0; s < 8; ++s) g[s] = xrow[(size_t)((ch + 1) * 8 + s) * NG];
      }
      __syncthreads();
    }

#pragma unroll 1
    for (int tt = 0; tt < 8; ++tt) {
      const int t = ch * 8 + tt;
      const int p = t & 1;

      float a0 = 0.f, a1 = 0.f, a2 = 0.f, a3 = 0.f;
      const f16x8* hv8 = reinterpret_cast<const f16x8*>(&hbuf[hf][p][kq][0]);
#pragma unroll
      for (int r8 = 0; r8 < 4; ++r8) {
        const f16x8 H = hv8[r8];
        const half2_t h0 = lo2(H, 0), h1 = lo2(H, 1), h2 = lo2(H, 2), h3 = lo2(H, 3);
        {
          const f16x8 W = wh8[0][r8];
          const half2_t w0 = lo2(W, 0), w1 = lo2(W, 1), w2 = lo2(W, 2), w3 = lo2(W, 3);
          a0 = fdot2(w0, h0, a0); a0 = fdot2(w1, h1, a0);
          a0 = fdot2(w2, h2, a0); a0 = fdot2(w3, h3, a0);
        }
        {
          const f16x8 W = wh8[1][r8];
          const half2_t w0 = lo2(W, 0), w1 = lo2(W, 1), w2 = lo2(W, 2), w3 = lo2(W, 3);
          a1 = fdot2(w0, h0, a1); a1 = fdot2(w1, h1, a1);
          a1 = fdot2(w2, h2, a1); a1 = fdot2(w3, h3, a1);
        }
        {
          const f16x8 W = wh8[2][r8];
          const half2_t w0 = lo2(W, 0), w1 = lo2(W, 1), w2 = lo2(W, 2), w3 = lo2(W, 3);
          a2 = fdot2(w0, h0, a2); a2 = fdot2(w1, h1, a2);
          a2 = fdot2(w2, h2, a2); a2 = fdot2(w3, h3, a2);
        }
        {
          const f16x8 W = wh8[3][r8];
          const half2_t w0 = lo2(W, 0), w1 = lo2(W, 1), w2 = lo2(W, 2), w3 = lo2(W, 3);
          a3 = fdot2(w0, h0, a3); a3 = fdot2(w1, h1, a3);
          a3 = fdot2(w2, h2, a3); a3 = fdot2(w3, h3, a3);
        }
      }
      // quad butterfly over kq lanes (lanes 4hf.. stay within the same quad)
      a0 += __shfl_xor(a0, 1, 4); a0 += __shfl_xor(a0, 2, 4);
      a1 += __shfl_xor(a1, 1, 4); a1 += __shfl_xor(a1, 2, 4);
      a2 += __shfl_xor(a2, 1, 4); a2 += __shfl_xor(a2, 2, 4);
      a3 += __shfl_xor(a3, 1, 4); a3 += __shfl_xor(a3, 2, 4);

      float xi, xf, xgg, xo;
      if (MODE == 2) {
        xi = xgc[hf][j]; xf = xgc[hf][j + 128];
        xgg = xgc[hf][j + 256]; xo = xgc[hf][j + 384];
      } else {
        const half_t* xb = &xgs[hf][ch & 1][tt][0];
        xi = (float)xb[j]; xf = (float)xb[j + 128];
        xgg = (float)xb[j + 256]; xo = (float)xb[j + 384];
      }

      const float ig = sigm(a0 + xi);
      const float fg = sigm(a1 + xf);
      const float gg = tanh_(a2 + xgg);
      const float og = sigm(a3 + xo);
      c = fmaf(fg, c, ig * gg);
      const float h = og * tanh_(c);

      if (kq == 0) {
        hbuf[hf][p ^ 1][j >> 5][j & 31] = (half_t)h;
        if (MODE != 1) seq_out[((size_t)b * NT + t) * NH + j] = (half_t)h;
        else if (t == NT - 1) hT_out[(size_t)b * NH + j] = h;
      }
      __syncthreads();
    }
  }
}

}  // namespace

extern "C" void kernel_launch(void* const* d_in, const int* in_sizes, int n_in,
                              void* d_out, int out_size, void* d_ws, size_t ws_size,
                              hipStream_t stream) {
  (void)in_sizes; (void)n_in; (void)out_size; (void)ws_size;

  const float* x     = (const float*)d_in[0];
  const float* e0Wih = (const float*)d_in[1];
  const float* e0Whh = (const float*)d_in[2];
  const float* e0bih = (const float*)d_in[3];
  const float* e0bhh = (const float*)d_in[4];
  const float* e1Wih = (const float*)d_in[5];
  const float* e1Whh = (const float*)d_in[6];
  const float* e1bih = (const float*)d_in[7];
  const float* e1bhh = (const float*)d_in[8];
  const float* d0Wih = (const float*)d_in[9];
  const float* d0Whh = (const float*)d_in[10];
  const float* d0bih = (const float*)d_in[11];
  const float* d0bhh = (const float*)d_in[12];
  const float* d1Wih = (const float*)d_in[13];
  const float* d1Whh = (const float*)d_in[14];
  const float* d1bih = (const float*)d_in[15];
  const float* d1bhh = (const float*)d_in[16];
  const float* Wout  = (const float*)d_in[17];
  const float* bout  = (const float*)d_in[18];
  float* out = (float*)d_out;

  // ---- workspace: Whh fp16 x4 | seqA fp16 [B*T,128] | xg fp16 [B*T,512] | hT f32 ----
  half_t* whh0 = (half_t*)d_ws;
  half_t* whh1 = whh0 + 512 * 128;
  half_t* whh2 = whh1 + 512 * 128;
  half_t* whh3 = whh2 + 512 * 128;
  half_t* seqA = whh3 + 512 * 128;
  half_t* xgb  = seqA + (size_t)NB * NT * NH;
  float*  hT   = (float*)(xgb + (size_t)NB * NT * NG);

  cvt_kernel<<<64, 256, 0, stream>>>(e0Whh, whh0, 512 * 128 / 4);
  cvt_kernel<<<64, 256, 0, stream>>>(e1Whh, whh1, 512 * 128 / 4);
  cvt_kernel<<<64, 256, 0, stream>>>(d0Whh, whh2, 512 * 128 / 4);
  cvt_kernel<<<64, 256, 0, stream>>>(d1Whh, whh3, 512 * 128 / 4);

  const int M = NB * NT;  // 131072
  dim3 gX(M / 128, NG / 64), gP(M / 128, 1), blkG(256);
  dim3 gR(NB / 2), blkR(1024);

  // enc0: xg0 = x @ e0Wih^T + b   (A fp32, K=64) -> rec -> seqA
  xg_gemm<64, true, false><<<gX, blkG, 0, stream>>>(x, e0Wih, e0bih, e0bhh, xgb, nullptr, NG);
  rec_kernel<0><<<gR, blkR, 0, stream>>>(xgb, nullptr, nullptr, nullptr, nullptr, whh0, seqA, nullptr);

  // enc1: xg1 = seqA @ e1Wih^T + b (A fp16, K=128) -> rec -> hT
  xg_gemm<128, false, false><<<gX, blkG, 0, stream>>>(seqA, e1Wih, e1bih, e1bhh, xgb, nullptr, NG);
  rec_kernel<1><<<gR, blkR, 0, stream>>>(xgb, nullptr, nullptr, nullptr, nullptr, whh1, nullptr, hT);

  // dec0: const xg from hT -> rec -> seqA
  rec_kernel<2><<<gR, blkR, 0, stream>>>(nullptr, hT, d0Wih, d0bih, d0bhh, whh2, seqA, nullptr);

  // dec1: xg3 = seqA @ d1Wih^T + b -> rec -> seqA (h-seq)
  xg_gemm<128, false, false><<<gX, blkG, 0, stream>>>(seqA, d1Wih, d1bih, d1bhh, xgb, nullptr, NG);
  rec_kernel<0><<<gR, blkR, 0, stream>>>(xgb, nullptr, nullptr, nullptr, nullptr, whh3, seqA, nullptr);

  // projection: out = seqA @ Wout^T + bout (fp32 out, N=64)
  xg_gemm<128, false, true><<<gP, blkG, 0, stream>>>(seqA, Wout, bout, nullptr, nullptr, out, 64);
}

// Round 9
// 2351.808 us; speedup vs baseline: 1.5202x; 1.3750x over previous
//
#include <hip/hip_runtime.h>
#include <cstddef>

namespace {

typedef _Float16 half_t;
typedef _Float16 half2_t __attribute__((ext_vector_type(2)));
typedef _Float16 f16x4 __attribute__((ext_vector_type(4)));
typedef _Float16 f16x8 __attribute__((ext_vector_type(8)));
typedef float f32x4 __attribute__((ext_vector_type(4)));

constexpr int NB = 256;  // batch
constexpr int NT = 512;  // time
constexpr int NH = 128;  // hidden
constexpr int NG = 512;  // 4*NH gates

__device__ __forceinline__ float sigm(float x) { return 1.0f / (1.0f + __expf(-x)); }
__device__ __forceinline__ float tanh_(float x) { return 2.0f / (1.0f + __expf(-2.0f * x)) - 1.0f; }
__device__ __forceinline__ float dot4(float4 w, float4 v, float acc) {
  return fmaf(w.x, v.x, fmaf(w.y, v.y, fmaf(w.z, v.z, fmaf(w.w, v.w, acc))));
}
__device__ __forceinline__ float fdot2(half2_t a, half2_t b, float c) {
  return __builtin_amdgcn_fdot2(a, b, c, false);  // v_dot2_f32_f16, f32 accum
}
__device__ __forceinline__ void pinv8(f16x8& x) { asm volatile("" : "+v"(x)); }

// fp32 -> fp16 conversion (Whh prep)
__global__ void cvt_kernel(const float* __restrict__ s, half_t* __restrict__ d, int n4) {
  int i = blockIdx.x * blockDim.x + threadIdx.x;
  if (i < n4) {
    float4 v = reinterpret_cast<const float4*>(s)[i];
    f16x4 hv = {(half_t)v.x, (half_t)v.y, (half_t)v.z, (half_t)v.w};
    reinterpret_cast<f16x4*>(d)[i] = hv;
  }
}

// ============ MFMA GEMM: C = A[M,K] * B[N,K]^T + b0 + b1 ============
// BM=128, BN=64, 256 threads = 4 waves.
// fp16 out: unit-interleaved xg layout  C[m][ (n&127)*4 + (n>>7) ]  (m = b*NT+t)
// fp32 out: projection C[m][n] with row stride Nstr.
template <int K, bool AF32, bool F32OUT>
__global__ __launch_bounds__(256) void xg_gemm(
    const void* __restrict__ Ap, const float* __restrict__ Bw,
    const float* __restrict__ b0, const float* __restrict__ b1,
    half_t* __restrict__ Ch, float* __restrict__ Cf, int Nstr)
{
  __shared__ __align__(16) half_t Atile[128 * K];
  __shared__ __align__(16) half_t Btile[64 * K];
  const int tid = threadIdx.x;
  const int m0 = blockIdx.x * 128;
  const int n0 = blockIdx.y * 64;
  char* Ab = (char*)Atile;
  char* Bb = (char*)Btile;

  if (AF32) {
    const float* Af = (const float*)Ap;
    for (int idx = tid; idx < 128 * K / 4; idx += 256) {
      int row = idx / (K / 4), o = idx % (K / 4);
      float4 v = *(const float4*)(Af + (size_t)(m0 + row) * K + 4 * o);
      f16x4 hv = {(half_t)v.x, (half_t)v.y, (half_t)v.z, (half_t)v.w};
      int byte = ((row * K + 4 * o) * 2) ^ ((row & 7) << 4);
      *(f16x4*)(Ab + byte) = hv;
    }
  } else {
    const half_t* Ah = (const half_t*)Ap;
    for (int idx = tid; idx < 128 * K / 8; idx += 256) {
      int row = idx / (K / 8), o = idx % (K / 8);
      uint4 v = *(const uint4*)(Ah + (size_t)(m0 + row) * K + 8 * o);
      int byte = ((row * K + 8 * o) * 2) ^ ((row & 7) << 4);
      *(uint4*)(Ab + byte) = v;
    }
  }
  for (int idx = tid; idx < 64 * K / 4; idx += 256) {
    int row = idx / (K / 4), o = idx % (K / 4);
    float4 v = *(const float4*)(Bw + (size_t)(n0 + row) * K + 4 * o);
    f16x4 hv = {(half_t)v.x, (half_t)v.y, (half_t)v.z, (half_t)v.w};
    int byte = ((row * K + 4 * o) * 2) ^ ((row & 7) << 4);
    *(f16x4*)(Bb + byte) = hv;
  }
  __syncthreads();

  const int lane = tid & 63, w = tid >> 6;
  const int r16 = lane & 15, koff = (lane >> 4) * 8;
  f32x4 acc[2][4];
#pragma unroll
  for (int fm = 0; fm < 2; ++fm)
#pragma unroll
    for (int fn = 0; fn < 4; ++fn) acc[fm][fn] = (f32x4){0.f, 0.f, 0.f, 0.f};

#pragma unroll
  for (int ks = 0; ks < K / 32; ++ks) {
    f16x8 a[2], bf[4];
#pragma unroll
    for (int fm = 0; fm < 2; ++fm) {
      int row = w * 32 + fm * 16 + r16;
      int byte = ((row * K + ks * 32 + koff) * 2) ^ ((row & 7) << 4);
      a[fm] = *(const f16x8*)(Ab + byte);
    }
#pragma unroll
    for (int fn = 0; fn < 4; ++fn) {
      int row = fn * 16 + r16;
      int byte = ((row * K + ks * 32 + koff) * 2) ^ ((row & 7) << 4);
      bf[fn] = *(const f16x8*)(Bb + byte);
    }
#pragma unroll
    for (int fm = 0; fm < 2; ++fm)
#pragma unroll
      for (int fn = 0; fn < 4; ++fn)
        acc[fm][fn] = __builtin_amdgcn_mfma_f32_16x16x32_f16(a[fm], bf[fn], acc[fm][fn], 0, 0, 0);
  }

  // D layout: col = lane&15, row = (lane>>4)*4 + q
#pragma unroll
  for (int fm = 0; fm < 2; ++fm)
#pragma unroll
    for (int fn = 0; fn < 4; ++fn) {
      int n = n0 + fn * 16 + r16;
      float bb = (b0 ? b0[n] : 0.f) + (b1 ? b1[n] : 0.f);
#pragma unroll
      for (int q = 0; q < 4; ++q) {
        int m = m0 + w * 32 + fm * 16 + (lane >> 4) * 4 + q;
        float val = acc[fm][fn][q] + bb;
        if (F32OUT) Cf[(size_t)m * Nstr + n] = val;
        else        Ch[(size_t)m * NG + ((n & 127) << 2) + (n >> 7)] = (half_t)val;
      }
    }
}

// ============ Recurrent kernel ============
// 256 blocks x 512 threads (8 waves = 2/SIMD), 1 batch/block.
// j = tid>>2 hidden unit, kq = tid&3 k-quarter. Whh resident (64 VGPR, pinned).
// Per step: 4 ds_read_b128 (h bcast) + 64 fdot2 in 16 independent depth-4
// chains + 8 ds_swizzle + gates + 1 barrier. xg read straight from global
// (unit-interleaved 8-B f16x4), register-prefetched 2 steps ahead -- no LDS
// staging.
// MODE: 0 = xg-stream -> seq-out (enc0, dec1)
//       1 = xg-stream -> hT-out  (enc1)
//       2 = const-xg  -> seq-out (dec0; xg from hT_in, computed once)
template <int MODE>
__global__ __attribute__((amdgpu_flat_work_group_size(512, 512)))
__attribute__((amdgpu_waves_per_eu(2, 2))) void rec_kernel(
    const half_t* __restrict__ xg,     // [NB*NT][NG] fp16, unit-interleaved
    const float* __restrict__ hT_in,   // [NB,NH]        (mode 2)
    const float* __restrict__ WihD,    // [NG,NH] fp32   (mode 2)
    const float* __restrict__ bih, const float* __restrict__ bhh,  // (mode 2)
    const half_t* __restrict__ Whh,    // [NG,NH] fp16
    half_t* __restrict__ seq_out,      // [NB,NT,NH] fp16 (modes 0/2)
    float* __restrict__ hT_out)        // [NB,NH]         (mode 1)
{
  const int b = blockIdx.x;
  const int tid = threadIdx.x;
  const int j = tid >> 2;
  const int kq = tid & 3;

  // h double-buffer: quarters padded to 48 halfs (96 B) -> bases on banks
  // {0,24,16,8}; uniform-address broadcast b128 reads, conflict-free.
  __shared__ __align__(16) half_t hbuf[2][4][48];
  __shared__ float xgc[NG];   // mode 2 scratch
  __shared__ float hinf[NH];  // mode 2 scratch

  // Resident recurrent weights: 4 gates x 32 k = 16 x f16x8 (64 VGPRs), pinned.
  f16x8 wh8[4][4];
#pragma unroll
  for (int gi = 0; gi < 4; ++gi) {
    const f16x8* p = reinterpret_cast<const f16x8*>(Whh + (size_t)(gi * NH + j) * NH + kq * 32);
#pragma unroll
    for (int r = 0; r < 4; ++r) wh8[gi][r] = p[r];
  }
#pragma unroll
  for (int gi = 0; gi < 4; ++gi)
#pragma unroll
    for (int r = 0; r < 4; ++r) pinv8(wh8[gi][r]);

  if (tid < NH) hbuf[0][tid >> 5][tid & 31] = (half_t)0.0f;  // h0 = 0
  float c = 0.0f;                                            // c0 (replicated x4 kq lanes)

  float cxi = 0.f, cxf = 0.f, cxg = 0.f, cxo = 0.f;  // mode-2 const xg
  if (MODE == 2) {
    if (tid < NH) hinf[tid] = hT_in[(size_t)b * NH + tid];
    __syncthreads();
    float a0 = bih[tid] + bhh[tid], a1 = 0.f, a2 = 0.f, a3 = 0.f;
    const float4* wr = (const float4*)(WihD + (size_t)tid * NH);
    const float4* hv = (const float4*)hinf;
#pragma unroll
    for (int k = 0; k < 8; ++k) {
      a0 = dot4(wr[4 * k + 0], hv[4 * k + 0], a0);
      a1 = dot4(wr[4 * k + 1], hv[4 * k + 1], a1);
      a2 = dot4(wr[4 * k + 2], hv[4 * k + 2], a2);
      a3 = dot4(wr[4 * k + 3], hv[4 * k + 3], a3);
    }
    xgc[tid] = (a0 + a1) + (a2 + a3);
    __syncthreads();
    cxi = xgc[j]; cxf = xgc[j + 128]; cxg = xgc[j + 256]; cxo = xgc[j + 384];
  }

  // xg prefetch, depth 2 (named regs; all 4 kq lanes load the same 8 B)
  const half_t* xbase = nullptr;
  f16x4 xqA = {}, xqB = {};
  if (MODE != 2) {
    xbase = xg + ((size_t)b * NT) * NG + (j << 2);
    xqA = *(const f16x4*)(xbase);
    xqB = *(const f16x4*)(xbase + NG);
  }

  __syncthreads();

  auto stepf = [&](int t, int p, f16x4& xq) {
    f16x4 cur = xq;
    if (MODE != 2 && t + 2 < NT)
      xq = *(const f16x4*)(xbase + (size_t)(t + 2) * NG);  // issue early, use in 2 steps

    const f16x8* hv8 = reinterpret_cast<const f16x8*>(&hbuf[p][kq][0]);

    // 16 independent depth-4 dot chains (4 gates x 4 k-sub-blocks)
    float pp[4][4];
#pragma unroll
    for (int gi = 0; gi < 4; ++gi)
#pragma unroll
      for (int r = 0; r < 4; ++r) pp[gi][r] = 0.f;
#pragma unroll
    for (int r8 = 0; r8 < 4; ++r8) {
      const f16x8 H = hv8[r8];
      const half2_t h0 = __builtin_shufflevector(H, H, 0, 1);
      const half2_t h1 = __builtin_shufflevector(H, H, 2, 3);
      const half2_t h2 = __builtin_shufflevector(H, H, 4, 5);
      const half2_t h3 = __builtin_shufflevector(H, H, 6, 7);
#pragma unroll
      for (int gi = 0; gi < 4; ++gi) {
        const f16x8 W = wh8[gi][r8];
        float s = pp[gi][r8];
        s = fdot2(__builtin_shufflevector(W, W, 0, 1), h0, s);
        s = fdot2(__builtin_shufflevector(W, W, 2, 3), h1, s);
        s = fdot2(__builtin_shufflevector(W, W, 4, 5), h2, s);
        s = fdot2(__builtin_shufflevector(W, W, 6, 7), h3, s);
        pp[gi][r8] = s;
      }
    }
    float a0 = (pp[0][0] + pp[0][1]) + (pp[0][2] + pp[0][3]);
    float a1 = (pp[1][0] + pp[1][1]) + (pp[1][2] + pp[1][3]);
    float a2 = (pp[2][0] + pp[2][1]) + (pp[2][2] + pp[2][3]);
    float a3 = (pp[3][0] + pp[3][1]) + (pp[3][2] + pp[3][3]);

    a0 += __shfl_xor(a0, 1, 4); a0 += __shfl_xor(a0, 2, 4);
    a1 += __shfl_xor(a1, 1, 4); a1 += __shfl_xor(a1, 2, 4);
    a2 += __shfl_xor(a2, 1, 4); a2 += __shfl_xor(a2, 2, 4);
    a3 += __shfl_xor(a3, 1, 4); a3 += __shfl_xor(a3, 2, 4);

    float xi, xf, xgg, xo;
    if (MODE == 2) {
      xi = cxi; xf = cxf; xgg = cxg; xo = cxo;
    } else {
      xi = (float)cur[0]; xf = (float)cur[1];
      xgg = (float)cur[2]; xo = (float)cur[3];
    }

    const float ig = sigm(a0 + xi);
    const float fg = sigm(a1 + xf);
    const float gg = tanh_(a2 + xgg);
    const float og = sigm(a3 + xo);
    c = fmaf(fg, c, ig * gg);
    const float h = og * tanh_(c);

    if (kq == 0) {
      hbuf[p ^ 1][j >> 5][j & 31] = (half_t)h;
      if (MODE != 1) seq_out[((size_t)b * NT + t) * NH + j] = (half_t)h;
      else if (t == NT - 1) hT_out[(size_t)b * NH + j] = h;
    }
    __syncthreads();
  };

#pragma unroll 1
  for (int t = 0; t < NT; t += 2) {
    stepf(t, 0, xqA);
    stepf(t + 1, 1, xqB);
  }
}

}  // namespace

extern "C" void kernel_launch(void* const* d_in, const int* in_sizes, int n_in,
                              void* d_out, int out_size, void* d_ws, size_t ws_size,
                              hipStream_t stream) {
  (void)in_sizes; (void)n_in; (void)out_size; (void)ws_size;

  const float* x     = (const float*)d_in[0];
  const float* e0Wih = (const float*)d_in[1];
  const float* e0Whh = (const float*)d_in[2];
  const float* e0bih = (const float*)d_in[3];
  const float* e0bhh = (const float*)d_in[4];
  const float* e1Wih = (const float*)d_in[5];
  const float* e1Whh = (const float*)d_in[6];
  const float* e1bih = (const float*)d_in[7];
  const float* e1bhh = (const float*)d_in[8];
  const float* d0Wih = (const float*)d_in[9];
  const float* d0Whh = (const float*)d_in[10];
  const float* d0bih = (const float*)d_in[11];
  const float* d0bhh = (const float*)d_in[12];
  const float* d1Wih = (const float*)d_in[13];
  const float* d1Whh = (const float*)d_in[14];
  const float* d1bih = (const float*)d_in[15];
  const float* d1bhh = (const float*)d_in[16];
  const float* Wout  = (const float*)d_in[17];
  const float* bout  = (const float*)d_in[18];
  float* out = (float*)d_out;

  // ---- workspace: Whh fp16 x4 | seqA fp16 [B*T,128] | xg fp16 [B*T,512] | hT f32 ----
  half_t* whh0 = (half_t*)d_ws;
  half_t* whh1 = whh0 + 512 * 128;
  half_t* whh2 = whh1 + 512 * 128;
  half_t* whh3 = whh2 + 512 * 128;
  half_t* seqA = whh3 + 512 * 128;
  half_t* xgb  = seqA + (size_t)NB * NT * NH;
  float*  hT   = (float*)(xgb + (size_t)NB * NT * NG);

  cvt_kernel<<<64, 256, 0, stream>>>(e0Whh, whh0, 512 * 128 / 4);
  cvt_kernel<<<64, 256, 0, stream>>>(e1Whh, whh1, 512 * 128 / 4);
  cvt_kernel<<<64, 256, 0, stream>>>(d0Whh, whh2, 512 * 128 / 4);
  cvt_kernel<<<64, 256, 0, stream>>>(d1Whh, whh3, 512 * 128 / 4);

  const int M = NB * NT;  // 131072
  dim3 gX(M / 128, NG / 64), gP(M / 128, 1), blkG(256);
  dim3 gR(NB), blkR(512);

  // enc0: xg0 = x @ e0Wih^T + b   (A fp32, K=64) -> rec -> seqA
  xg_gemm<64, true, false><<<gX, blkG, 0, stream>>>(x, e0Wih, e0bih, e0bhh, xgb, nullptr, NG);
  rec_kernel<0><<<gR, blkR, 0, stream>>>(xgb, nullptr, nullptr, nullptr, nullptr, whh0, seqA, nullptr);

  // enc1: xg1 = seqA @ e1Wih^T + b (A fp16, K=128) -> rec -> hT
  xg_gemm<128, false, false><<<gX, blkG, 0, stream>>>(seqA, e1Wih, e1bih, e1bhh, xgb, nullptr, NG);
  rec_kernel<1><<<gR, blkR, 0, stream>>>(xgb, nullptr, nullptr, nullptr, nullptr, whh1, nullptr, hT);

  // dec0: const xg from hT -> rec -> seqA
  rec_kernel<2><<<gR, blkR, 0, stream>>>(nullptr, hT, d0Wih, d0bih, d0bhh, whh2, seqA, nullptr);

  // dec1: xg3 = seqA @ d1Wih^T + b -> rec -> seqA (h-seq)
  xg_gemm<128, false, false><<<gX, blkG, 0, stream>>>(seqA, d1Wih, d1bih, d1bhh, xgb, nullptr, NG);
  rec_kernel<0><<<gR, blkR, 0, stream>>>(xgb, nullptr, nullptr, nullptr, nullptr, whh3, seqA, nullptr);

  // projection: out = seqA @ Wout^T + bout (fp32 out, N=64)
  xg_gemm<128, false, true><<<gP, blkG, 0, stream>>>(seqA, Wout, bout, nullptr, nullptr, out, 64);
}

// Round 10
// 1861.165 us; speedup vs baseline: 1.9210x; 1.2636x over previous
//
#include <hip/hip_runtime.h>
#include <cstddef>

namespace {

typedef _Float16 half_t;
typedef _Float16 half2_t __attribute__((ext_vector_type(2)));
typedef _Float16 f16x4 __attribute__((ext_vector_type(4)));
typedef _Float16 f16x8 __attribute__((ext_vector_type(8)));
typedef float f32x4 __attribute__((ext_vector_type(4)));

constexpr int NB = 256;  // batch
constexpr int NT = 512;  // time
constexpr int NH = 128;  // hidden
constexpr int NG = 512;  // 4*NH gates

__device__ __forceinline__ float sigm(float x) { return 1.0f / (1.0f + __expf(-x)); }
__device__ __forceinline__ float tanh_(float x) { return 2.0f / (1.0f + __expf(-2.0f * x)) - 1.0f; }
__device__ __forceinline__ float dot4(float4 w, float4 v, float acc) {
  return fmaf(w.x, v.x, fmaf(w.y, v.y, fmaf(w.z, v.z, fmaf(w.w, v.w, acc))));
}
__device__ __forceinline__ float fdot2(half2_t a, half2_t b, float c) {
  return __builtin_amdgcn_fdot2(a, b, c, false);  // v_dot2_f32_f16, f32 accum
}
__device__ __forceinline__ void pinv8(f16x8& x) { asm volatile("" : "+v"(x)); }

// quad (4-lane) sum via DPP quad_perm -- VALU, not LDS pipe (ds_swizzle).
__device__ __forceinline__ float qreduce(float v) {
  int t = __builtin_amdgcn_update_dpp(0, __float_as_int(v), 0xB1, 0xF, 0xF, true);  // [1,0,3,2]
  v += __int_as_float(t);
  t = __builtin_amdgcn_update_dpp(0, __float_as_int(v), 0x4E, 0xF, 0xF, true);      // [2,3,0,1]
  return v + __int_as_float(t);
}

// fp32 -> fp16 conversion (Whh prep)
__global__ void cvt_kernel(const float* __restrict__ s, half_t* __restrict__ d, int n4) {
  int i = blockIdx.x * blockDim.x + threadIdx.x;
  if (i < n4) {
    float4 v = reinterpret_cast<const float4*>(s)[i];
    f16x4 hv = {(half_t)v.x, (half_t)v.y, (half_t)v.z, (half_t)v.w};
    reinterpret_cast<f16x4*>(d)[i] = hv;
  }
}

// ============ MFMA GEMM: C = A[M,K] * B[N,K]^T + biases ============
// BM=128, BN=64, 256 threads = 4 waves.
// !F32OUT: B rows permuted at load (orig = (n&3)*128 + (n>>2)) so output column
//          n is the unit-interleaved gate index; epilogue stores Ch[m*NG+n]
//          with r4's (proven-fast) pattern.
// F32OUT : projection, unpermuted, Cf[m*Nstr+n].
template <int K, bool AF32, bool F32OUT>
__global__ __launch_bounds__(256) void xg_gemm(
    const void* __restrict__ Ap, const float* __restrict__ Bw,
    const float* __restrict__ b0, const float* __restrict__ b1,
    half_t* __restrict__ Ch, float* __restrict__ Cf, int Nstr)
{
  __shared__ __align__(16) half_t Atile[128 * K];
  __shared__ __align__(16) half_t Btile[64 * K];
  const int tid = threadIdx.x;
  const int m0 = blockIdx.x * 128;
  const int n0 = blockIdx.y * 64;
  char* Ab = (char*)Atile;
  char* Bb = (char*)Btile;

  if (AF32) {
    const float* Af = (const float*)Ap;
    for (int idx = tid; idx < 128 * K / 4; idx += 256) {
      int row = idx / (K / 4), o = idx % (K / 4);
      float4 v = *(const float4*)(Af + (size_t)(m0 + row) * K + 4 * o);
      f16x4 hv = {(half_t)v.x, (half_t)v.y, (half_t)v.z, (half_t)v.w};
      int byte = ((row * K + 4 * o) * 2) ^ ((row & 7) << 4);
      *(f16x4*)(Ab + byte) = hv;
    }
  } else {
    const half_t* Ah = (const half_t*)Ap;
    for (int idx = tid; idx < 128 * K / 8; idx += 256) {
      int row = idx / (K / 8), o = idx % (K / 8);
      uint4 v = *(const uint4*)(Ah + (size_t)(m0 + row) * K + 8 * o);
      int byte = ((row * K + 8 * o) * 2) ^ ((row & 7) << 4);
      *(uint4*)(Ab + byte) = v;
    }
  }
  for (int idx = tid; idx < 64 * K / 4; idx += 256) {
    int row = idx / (K / 4), o = idx % (K / 4);
    int n = n0 + row;
    int src_row = F32OUT ? n : ((n & 3) * 128 + (n >> 2));  // gate-interleave permutation
    float4 v = *(const float4*)(Bw + (size_t)src_row * K + 4 * o);
    f16x4 hv = {(half_t)v.x, (half_t)v.y, (half_t)v.z, (half_t)v.w};
    int byte = ((row * K + 4 * o) * 2) ^ ((row & 7) << 4);
    *(f16x4*)(Bb + byte) = hv;
  }
  __syncthreads();

  const int lane = tid & 63, w = tid >> 6;
  const int r16 = lane & 15, koff = (lane >> 4) * 8;
  f32x4 acc[2][4];
#pragma unroll
  for (int fm = 0; fm < 2; ++fm)
#pragma unroll
    for (int fn = 0; fn < 4; ++fn) acc[fm][fn] = (f32x4){0.f, 0.f, 0.f, 0.f};

#pragma unroll
  for (int ks = 0; ks < K / 32; ++ks) {
    f16x8 a[2], bf[4];
#pragma unroll
    for (int fm = 0; fm < 2; ++fm) {
      int row = w * 32 + fm * 16 + r16;
      int byte = ((row * K + ks * 32 + koff) * 2) ^ ((row & 7) << 4);
      a[fm] = *(const f16x8*)(Ab + byte);
    }
#pragma unroll
    for (int fn = 0; fn < 4; ++fn) {
      int row = fn * 16 + r16;
      int byte = ((row * K + ks * 32 + koff) * 2) ^ ((row & 7) << 4);
      bf[fn] = *(const f16x8*)(Bb + byte);
    }
#pragma unroll
    for (int fm = 0; fm < 2; ++fm)
#pragma unroll
      for (int fn = 0; fn < 4; ++fn)
        acc[fm][fn] = __builtin_amdgcn_mfma_f32_16x16x32_f16(a[fm], bf[fn], acc[fm][fn], 0, 0, 0);
  }

  // D layout: col = lane&15, row = (lane>>4)*4 + q
#pragma unroll
  for (int fm = 0; fm < 2; ++fm)
#pragma unroll
    for (int fn = 0; fn < 4; ++fn) {
      int n = n0 + fn * 16 + r16;
      int bidx = F32OUT ? n : ((n & 3) * 128 + (n >> 2));  // bias at original gate id
      float bb = (b0 ? b0[bidx] : 0.f) + (b1 ? b1[bidx] : 0.f);
#pragma unroll
      for (int q = 0; q < 4; ++q) {
        int m = m0 + w * 32 + fm * 16 + (lane >> 4) * 4 + q;
        float val = acc[fm][fn][q] + bb;
        if (F32OUT) Cf[(size_t)m * Nstr + n] = val;
        else        Ch[(size_t)m * NG + n] = (half_t)val;
      }
    }
}

// ============ Recurrent kernel ============
// 256 blocks x 512 threads (8 waves = 2/SIMD), 1 batch/block.
// j = tid>>2 hidden unit, kq = tid&3 k-quarter. Whh resident (64 VGPR, pinned).
// Per step: 4 ds_read_b128 (h bcast, only LDS user) + 64 fdot2 (8 indep chains)
// + 8 DPP quad_perm (VALU reduce -- r9's ds_swizzle was on the shared LDS pipe)
// + gates + 1 barrier. xg read from global (unit-interleaved f16x4),
// register-prefetched 2 steps ahead.
// MODE: 0 = xg-stream -> seq-out (enc0, dec1)
//       1 = xg-stream -> hT-out  (enc1)
//       2 = const-xg  -> seq-out (dec0; xg from hT_in, computed once)
template <int MODE>
__global__ __attribute__((amdgpu_flat_work_group_size(512, 512)))
__attribute__((amdgpu_waves_per_eu(2, 2))) void rec_kernel(
    const half_t* __restrict__ xg,     // [NB*NT][NG] fp16, unit-interleaved
    const float* __restrict__ hT_in,   // [NB,NH]        (mode 2)
    const float* __restrict__ WihD,    // [NG,NH] fp32   (mode 2)
    const float* __restrict__ bih, const float* __restrict__ bhh,  // (mode 2)
    const half_t* __restrict__ Whh,    // [NG,NH] fp16
    half_t* __restrict__ seq_out,      // [NB,NT,NH] fp16 (modes 0/2)
    float* __restrict__ hT_out)        // [NB,NH]         (mode 1)
{
  const int b = blockIdx.x;
  const int tid = threadIdx.x;
  const int j = tid >> 2;
  const int kq = tid & 3;

  // h double-buffer: quarters padded to 48 halfs (96 B) -> bases on banks
  // {0,24,16,8}; uniform-address broadcast b128 reads, conflict-free.
  __shared__ __align__(16) half_t hbuf[2][4][48];
  __shared__ float xgc[NG];   // mode 2 scratch
  __shared__ float hinf[NH];  // mode 2 scratch

  // Resident recurrent weights: 4 gates x 32 k = 16 x f16x8 (64 VGPRs), pinned.
  f16x8 wh8[4][4];
#pragma unroll
  for (int gi = 0; gi < 4; ++gi) {
    const f16x8* p = reinterpret_cast<const f16x8*>(Whh + (size_t)(gi * NH + j) * NH + kq * 32);
#pragma unroll
    for (int r = 0; r < 4; ++r) wh8[gi][r] = p[r];
  }
#pragma unroll
  for (int gi = 0; gi < 4; ++gi)
#pragma unroll
    for (int r = 0; r < 4; ++r) pinv8(wh8[gi][r]);

  if (tid < NH) hbuf[0][tid >> 5][tid & 31] = (half_t)0.0f;  // h0 = 0
  float c = 0.0f;                                            // c0 (replicated x4 kq lanes)

  float cxi = 0.f, cxf = 0.f, cxg = 0.f, cxo = 0.f;  // mode-2 const xg
  if (MODE == 2) {
    if (tid < NH) hinf[tid] = hT_in[(size_t)b * NH + tid];
    __syncthreads();
    float a0 = bih[tid] + bhh[tid], a1 = 0.f, a2 = 0.f, a3 = 0.f;
    const float4* wr = (const float4*)(WihD + (size_t)tid * NH);
    const float4* hv = (const float4*)hinf;
#pragma unroll
    for (int k = 0; k < 8; ++k) {
      a0 = dot4(wr[4 * k + 0], hv[4 * k + 0], a0);
      a1 = dot4(wr[4 * k + 1], hv[4 * k + 1], a1);
      a2 = dot4(wr[4 * k + 2], hv[4 * k + 2], a2);
      a3 = dot4(wr[4 * k + 3], hv[4 * k + 3], a3);
    }
    xgc[tid] = (a0 + a1) + (a2 + a3);
    __syncthreads();
    cxi = xgc[j]; cxf = xgc[j + 128]; cxg = xgc[j + 256]; cxo = xgc[j + 384];
  }

  // xg prefetch, depth 2 (named regs; the 4 kq lanes load the same 8 B)
  const half_t* xbase = nullptr;
  f16x4 xqA = {}, xqB = {};
  if (MODE != 2) {
    xbase = xg + ((size_t)b * NT) * NG + (j << 2);
    xqA = *(const f16x4*)(xbase);
    xqB = *(const f16x4*)(xbase + NG);
  }

  __syncthreads();

  auto stepf = [&](int t, int p, f16x4& xq) {
    f16x4 cur = xq;
    if (MODE != 2 && t + 2 < NT)
      xq = *(const f16x4*)(xbase + (size_t)(t + 2) * NG);  // issue early, use in 2 steps

    const f16x8* hv8 = reinterpret_cast<const f16x8*>(&hbuf[p][kq][0]);

    // 8 independent dot chains (4 gates x 2 halves); xg folded into chain init.
    float pa[4], pb[4];
    if (MODE == 2) {
      pa[0] = cxi * 0.25f; pa[1] = cxf * 0.25f; pa[2] = cxg * 0.25f; pa[3] = cxo * 0.25f;
    } else {
#pragma unroll
      for (int gi = 0; gi < 4; ++gi) pa[gi] = (float)cur[gi] * 0.25f;
    }
#pragma unroll
    for (int gi = 0; gi < 4; ++gi) pb[gi] = 0.f;

#pragma unroll
    for (int r8 = 0; r8 < 4; ++r8) {
      const f16x8 H = hv8[r8];
      const half2_t h0 = __builtin_shufflevector(H, H, 0, 1);
      const half2_t h1 = __builtin_shufflevector(H, H, 2, 3);
      const half2_t h2 = __builtin_shufflevector(H, H, 4, 5);
      const half2_t h3 = __builtin_shufflevector(H, H, 6, 7);
#pragma unroll
      for (int gi = 0; gi < 4; ++gi) {
        const f16x8 W = wh8[gi][r8];
        float sa = pa[gi], sb = pb[gi];
        sa = fdot2(__builtin_shufflevector(W, W, 0, 1), h0, sa);
        sb = fdot2(__builtin_shufflevector(W, W, 2, 3), h1, sb);
        sa = fdot2(__builtin_shufflevector(W, W, 4, 5), h2, sa);
        sb = fdot2(__builtin_shufflevector(W, W, 6, 7), h3, sb);
        pa[gi] = sa; pb[gi] = sb;
      }
    }
    // quad sum on the VALU (DPP quad_perm), not the LDS pipe.
    // Note: xg/4 was folded into each lane's pa -> sums back to full xg.
    const float a0 = qreduce(pa[0] + pb[0]);
    const float a1 = qreduce(pa[1] + pb[1]);
    const float a2 = qreduce(pa[2] + pb[2]);
    const float a3 = qreduce(pa[3] + pb[3]);

    const float ig = sigm(a0);
    const float fg = sigm(a1);
    const float gg = tanh_(a2);
    const float og = sigm(a3);
    c = fmaf(fg, c, ig * gg);
    const float h = og * tanh_(c);

    if (kq == 0) {
      hbuf[p ^ 1][j >> 5][j & 31] = (half_t)h;
      if (MODE != 1) seq_out[((size_t)b * NT + t) * NH + j] = (half_t)h;
      else if (t == NT - 1) hT_out[(size_t)b * NH + j] = h;
    }
    __syncthreads();
  };

#pragma unroll 1
  for (int t = 0; t < NT; t += 2) {
    stepf(t, 0, xqA);
    stepf(t + 1, 1, xqB);
  }
}

}  // namespace

extern "C" void kernel_launch(void* const* d_in, const int* in_sizes, int n_in,
                              void* d_out, int out_size, void* d_ws, size_t ws_size,
                              hipStream_t stream) {
  (void)in_sizes; (void)n_in; (void)out_size; (void)ws_size;

  const float* x     = (const float*)d_in[0];
  const float* e0Wih = (const float*)d_in[1];
  const float* e0Whh = (const float*)d_in[2];
  const float* e0bih = (const float*)d_in[3];
  const float* e0bhh = (const float*)d_in[4];
  const float* e1Wih = (const float*)d_in[5];
  const float* e1Whh = (const float*)d_in[6];
  const float* e1bih = (const float*)d_in[7];
  const float* e1bhh = (const float*)d_in[8];
  const float* d0Wih = (const float*)d_in[9];
  const float* d0Whh = (const float*)d_in[10];
  const float* d0bih = (const float*)d_in[11];
  const float* d0bhh = (const float*)d_in[12];
  const float* d1Wih = (const float*)d_in[13];
  const float* d1Whh = (const float*)d_in[14];
  const float* d1bih = (const float*)d_in[15];
  const float* d1bhh = (const float*)d_in[16];
  const float* Wout  = (const float*)d_in[17];
  const float* bout  = (const float*)d_in[18];
  float* out = (float*)d_out;

  // ---- workspace: Whh fp16 x4 | seqA fp16 [B*T,128] | xg fp16 [B*T,512] | hT f32 ----
  half_t* whh0 = (half_t*)d_ws;
  half_t* whh1 = whh0 + 512 * 128;
  half_t* whh2 = whh1 + 512 * 128;
  half_t* whh3 = whh2 + 512 * 128;
  half_t* seqA = whh3 + 512 * 128;
  half_t* xgb  = seqA + (size_t)NB * NT * NH;
  float*  hT   = (float*)(xgb + (size_t)NB * NT * NG);

  cvt_kernel<<<64, 256, 0, stream>>>(e0Whh, whh0, 512 * 128 / 4);
  cvt_kernel<<<64, 256, 0, stream>>>(e1Whh, whh1, 512 * 128 / 4);
  cvt_kernel<<<64, 256, 0, stream>>>(d0Whh, whh2, 512 * 128 / 4);
  cvt_kernel<<<64, 256, 0, stream>>>(d1Whh, whh3, 512 * 128 / 4);

  const int M = NB * NT;  // 131072
  dim3 gX(M / 128, NG / 64), gP(M / 128, 1), blkG(256);
  dim3 gR(NB), blkR(512);

  // enc0: xg0 = x @ e0Wih^T + b   (A fp32, K=64) -> rec -> seqA
  xg_gemm<64, true, false><<<gX, blkG, 0, stream>>>(x, e0Wih, e0bih, e0bhh, xgb, nullptr, NG);
  rec_kernel<0><<<gR, blkR, 0, stream>>>(xgb, nullptr, nullptr, nullptr, nullptr, whh0, seqA, nullptr);

  // enc1: xg1 = seqA @ e1Wih^T + b (A fp16, K=128) -> rec -> hT
  xg_gemm<128, false, false><<<gX, blkG, 0, stream>>>(seqA, e1Wih, e1bih, e1bhh, xgb, nullptr, NG);
  rec_kernel<1><<<gR, blkR, 0, stream>>>(xgb, nullptr, nullptr, nullptr, nullptr, whh1, nullptr, hT);

  // dec0: const xg from hT -> rec -> seqA
  rec_kernel<2><<<gR, blkR, 0, stream>>>(nullptr, hT, d0Wih, d0bih, d0bhh, whh2, seqA, nullptr);

  // dec1: xg3 = seqA @ d1Wih^T + b -> rec -> seqA (h-seq)
  xg_gemm<128, false, false><<<gX, blkG, 0, stream>>>(seqA, d1Wih, d1bih, d1bhh, xgb, nullptr, NG);
  rec_kernel<0><<<gR, blkR, 0, stream>>>(xgb, nullptr, nullptr, nullptr, nullptr, whh3, seqA, nullptr);

  // projection: out = seqA @ Wout^T + bout (fp32 out, N=64)
  xg_gemm<128, false, true><<<gP, blkG, 0, stream>>>(seqA, Wout, bout, nullptr, nullptr, out, 64);
}

// Round 11
// 1790.217 us; speedup vs baseline: 1.9971x; 1.0396x over previous
//
#include <hip/hip_runtime.h>
#include <cstddef>

namespace {

typedef _Float16 half_t;
typedef _Float16 half2_t __attribute__((ext_vector_type(2)));
typedef _Float16 f16x4 __attribute__((ext_vector_type(4)));
typedef _Float16 f16x8 __attribute__((ext_vector_type(8)));
typedef float f32x4 __attribute__((ext_vector_type(4)));

constexpr int NB = 256;  // batch
constexpr int NT = 512;  // time
constexpr int NH = 128;  // hidden
constexpr int NG = 512;  // 4*NH gates

__device__ __forceinline__ float sigm(float x) { return 1.0f / (1.0f + __expf(-x)); }
__device__ __forceinline__ float tanh_(float x) { return 2.0f / (1.0f + __expf(-2.0f * x)) - 1.0f; }
__device__ __forceinline__ float dot4(float4 w, float4 v, float acc) {
  return fmaf(w.x, v.x, fmaf(w.y, v.y, fmaf(w.z, v.z, fmaf(w.w, v.w, acc))));
}
__device__ __forceinline__ float fdot2(half2_t a, half2_t b, float c) {
  return __builtin_amdgcn_fdot2(a, b, c, false);  // v_dot2_f32_f16, f32 accum
}
__device__ __forceinline__ void pinv8(f16x8& x) { asm volatile("" : "+v"(x)); }

// quad (4-lane) sum via DPP quad_perm -- VALU, not LDS pipe.
__device__ __forceinline__ float qreduce(float v) {
  int t = __builtin_amdgcn_update_dpp(0, __float_as_int(v), 0xB1, 0xF, 0xF, true);  // [1,0,3,2]
  v += __int_as_float(t);
  t = __builtin_amdgcn_update_dpp(0, __float_as_int(v), 0x4E, 0xF, 0xF, true);      // [2,3,0,1]
  return v + __int_as_float(t);
}

// fp32 -> fp16 conversion (weight prep)
__global__ void cvt_kernel(const float* __restrict__ s, half_t* __restrict__ d, int n4) {
  int i = blockIdx.x * blockDim.x + threadIdx.x;
  if (i < n4) {
    float4 v = reinterpret_cast<const float4*>(s)[i];
    f16x4 hv = {(half_t)v.x, (half_t)v.y, (half_t)v.z, (half_t)v.w};
    reinterpret_cast<f16x4*>(d)[i] = hv;
  }
}

// ============ MFMA GEMM: C = A[M,K] * B[N,K]^T + biases ============  (r10, validated)
// !F32OUT: B rows permuted at load (orig = (n&3)*128 + (n>>2)) -> unit-interleaved
//          xg output Ch[m*NG+n]; F32OUT: projection Cf[m*Nstr+n].
template <int K, bool AF32, bool F32OUT>
__global__ __launch_bounds__(256) void xg_gemm(
    const void* __restrict__ Ap, const float* __restrict__ Bw,
    const float* __restrict__ b0, const float* __restrict__ b1,
    half_t* __restrict__ Ch, float* __restrict__ Cf, int Nstr)
{
  __shared__ __align__(16) half_t Atile[128 * K];
  __shared__ __align__(16) half_t Btile[64 * K];
  const int tid = threadIdx.x;
  const int m0 = blockIdx.x * 128;
  const int n0 = blockIdx.y * 64;
  char* Ab = (char*)Atile;
  char* Bb = (char*)Btile;

  if (AF32) {
    const float* Af = (const float*)Ap;
    for (int idx = tid; idx < 128 * K / 4; idx += 256) {
      int row = idx / (K / 4), o = idx % (K / 4);
      float4 v = *(const float4*)(Af + (size_t)(m0 + row) * K + 4 * o);
      f16x4 hv = {(half_t)v.x, (half_t)v.y, (half_t)v.z, (half_t)v.w};
      int byte = ((row * K + 4 * o) * 2) ^ ((row & 7) << 4);
      *(f16x4*)(Ab + byte) = hv;
    }
  } else {
    const half_t* Ah = (const half_t*)Ap;
    for (int idx = tid; idx < 128 * K / 8; idx += 256) {
      int row = idx / (K / 8), o = idx % (K / 8);
      uint4 v = *(const uint4*)(Ah + (size_t)(m0 + row) * K + 8 * o);
      int byte = ((row * K + 8 * o) * 2) ^ ((row & 7) << 4);
      *(uint4*)(Ab + byte) = v;
    }
  }
  for (int idx = tid; idx < 64 * K / 4; idx += 256) {
    int row = idx / (K / 4), o = idx % (K / 4);
    int n = n0 + row;
    int src_row = F32OUT ? n : ((n & 3) * 128 + (n >> 2));  // gate-interleave permutation
    float4 v = *(const float4*)(Bw + (size_t)src_row * K + 4 * o);
    f16x4 hv = {(half_t)v.x, (half_t)v.y, (half_t)v.z, (half_t)v.w};
    int byte = ((row * K + 4 * o) * 2) ^ ((row & 7) << 4);
    *(f16x4*)(Bb + byte) = hv;
  }
  __syncthreads();

  const int lane = tid & 63, w = tid >> 6;
  const int r16 = lane & 15, koff = (lane >> 4) * 8;
  f32x4 acc[2][4];
#pragma unroll
  for (int fm = 0; fm < 2; ++fm)
#pragma unroll
    for (int fn = 0; fn < 4; ++fn) acc[fm][fn] = (f32x4){0.f, 0.f, 0.f, 0.f};

#pragma unroll
  for (int ks = 0; ks < K / 32; ++ks) {
    f16x8 a[2], bf[4];
#pragma unroll
    for (int fm = 0; fm < 2; ++fm) {
      int row = w * 32 + fm * 16 + r16;
      int byte = ((row * K + ks * 32 + koff) * 2) ^ ((row & 7) << 4);
      a[fm] = *(const f16x8*)(Ab + byte);
    }
#pragma unroll
    for (int fn = 0; fn < 4; ++fn) {
      int row = fn * 16 + r16;
      int byte = ((row * K + ks * 32 + koff) * 2) ^ ((row & 7) << 4);
      bf[fn] = *(const f16x8*)(Bb + byte);
    }
#pragma unroll
    for (int fm = 0; fm < 2; ++fm)
#pragma unroll
      for (int fn = 0; fn < 4; ++fn)
        acc[fm][fn] = __builtin_amdgcn_mfma_f32_16x16x32_f16(a[fm], bf[fn], acc[fm][fn], 0, 0, 0);
  }

#pragma unroll
  for (int fm = 0; fm < 2; ++fm)
#pragma unroll
    for (int fn = 0; fn < 4; ++fn) {
      int n = n0 + fn * 16 + r16;
      int bidx = F32OUT ? n : ((n & 3) * 128 + (n >> 2));
      float bb = (b0 ? b0[bidx] : 0.f) + (b1 ? b1[bidx] : 0.f);
#pragma unroll
      for (int q = 0; q < 4; ++q) {
        int m = m0 + w * 32 + fm * 16 + (lane >> 4) * 4 + q;
        float val = acc[fm][fn][q] + bb;
        if (F32OUT) Cf[(size_t)m * Nstr + n] = val;
        else        Ch[(size_t)m * NG + n] = (half_t)val;
      }
    }
}

// ============ Fused 2-layer recurrent kernel (pipelined) ============
// 256 blocks x 512 threads (8 waves = 2/SIMD), 1 batch/block, j=tid>>2, kq=tid&3.
// Super-step s: L0 computes h0(s) [if s<NT]; L1 computes h1(s-1) from
// concat[h1(s-2); h0(s-1)] [if s>=1]. One barrier per super-step; 513 steps
// replace TWO 512-step sweeps (the per-step sync cost, not work, is the bound).
// L0: gates = xg0 (GEMM-precomputed, enc / const-from-hT, dec) + Whh0.h0(t-1).
// L1: gates = bias1 + [WhhC|WihC].[h1(t-2); h0(t-1)]  (input GEMM folded in).
// Pinned weights: 64 (L0) + 128 (L1 concat) VGPRs.
// ENC: writes hT only.  DEC: writes dec1 h-seq (for projection GEMM).
template <bool DEC>
__global__ __attribute__((amdgpu_flat_work_group_size(512, 512)))
__attribute__((amdgpu_waves_per_eu(2, 2))) void rec_fused(
    const half_t* __restrict__ xg0,    // [NB*NT][NG] unit-interleaved (enc)
    const float* __restrict__ hT_in,   // [NB,NH]   (dec)
    const float* __restrict__ Wih0_32, // [NG,NH] fp32 (dec: d0Wih)
    const float* __restrict__ b0a, const float* __restrict__ b0b,  // L0 biases (dec)
    const half_t* __restrict__ Whh0,   // [NG,NH] fp16
    const half_t* __restrict__ WhhC,   // [NG,NH] fp16 (L1 recurrent)
    const half_t* __restrict__ WihC,   // [NG,NH] fp16 (L1 input)
    const float* __restrict__ b1a, const float* __restrict__ b1b,  // L1 biases
    half_t* __restrict__ seq_out,      // [NB*NT][NH] (dec)
    float* __restrict__ hT_out)        // [NB,NH]     (enc)
{
  const int b = blockIdx.x;
  const int tid = threadIdx.x;
  const int j = tid >> 2;
  const int kq = tid & 3;

  // quarters padded to 48 halfs (96 B): bases on banks {0,24,16,8} per parity.
  __shared__ __align__(16) half_t h0buf[2][4][48];
  __shared__ __align__(16) half_t h1buf[2][4][48];
  __shared__ float xgc[NG];   // dec const-xg scratch
  __shared__ float hinf[NH];

  // L0 recurrent weights: 16 x f16x8 = 64 VGPRs, pinned.
  f16x8 wh0[4][4];
#pragma unroll
  for (int gi = 0; gi < 4; ++gi) {
    const f16x8* p = reinterpret_cast<const f16x8*>(Whh0 + (size_t)(gi * NH + j) * NH + kq * 32);
#pragma unroll
    for (int r = 0; r < 4; ++r) wh0[gi][r] = p[r];
  }
#pragma unroll
  for (int gi = 0; gi < 4; ++gi)
#pragma unroll
    for (int r = 0; r < 4; ++r) pinv8(wh0[gi][r]);

  // L1 concat weights: kq<2 -> WhhC (h1 dims), kq>=2 -> WihC (h0 dims);
  // cols (kq&1)*64..+64. 32 x f16x8 = 128 VGPRs, pinned.
  f16x8 wc[4][8];
  const half_t* cbase = (kq < 2) ? WhhC : WihC;
#pragma unroll
  for (int gi = 0; gi < 4; ++gi) {
    const f16x8* p =
        reinterpret_cast<const f16x8*>(cbase + (size_t)(gi * NH + j) * NH + (kq & 1) * 64);
#pragma unroll
    for (int r = 0; r < 8; ++r) wc[gi][r] = p[r];
  }
#pragma unroll
  for (int gi = 0; gi < 4; ++gi)
#pragma unroll
    for (int r = 0; r < 8; ++r) pinv8(wc[gi][r]);

  float b1g[4];  // L1 bias, /4-folded (quad-sum restores)
#pragma unroll
  for (int gi = 0; gi < 4; ++gi)
    b1g[gi] = (b1a[gi * NH + j] + b1b[gi * NH + j]) * 0.25f;

  if (tid < NH) {  // h0(-1)=0 (parity 1), h1(-1)=0 (parity 1)
    h0buf[1][tid >> 5][tid & 31] = (half_t)0.f;
    h1buf[1][tid >> 5][tid & 31] = (half_t)0.f;
  }

  float c0 = 0.f, c1 = 0.f;
  float cx[4] = {0.f, 0.f, 0.f, 0.f};  // dec L0 const xg, /4-folded

  if (DEC) {
    if (tid < NH) hinf[tid] = hT_in[(size_t)b * NH + tid];
    __syncthreads();
    float a0 = b0a[tid] + b0b[tid], a1 = 0.f, a2 = 0.f, a3 = 0.f;
    const float4* wr = (const float4*)(Wih0_32 + (size_t)tid * NH);
    const float4* hv = (const float4*)hinf;
#pragma unroll
    for (int k = 0; k < 8; ++k) {
      a0 = dot4(wr[4 * k + 0], hv[4 * k + 0], a0);
      a1 = dot4(wr[4 * k + 1], hv[4 * k + 1], a1);
      a2 = dot4(wr[4 * k + 2], hv[4 * k + 2], a2);
      a3 = dot4(wr[4 * k + 3], hv[4 * k + 3], a3);
    }
    xgc[tid] = (a0 + a1) + (a2 + a3);
    __syncthreads();
    cx[0] = xgc[j] * 0.25f;       cx[1] = xgc[j + 128] * 0.25f;
    cx[2] = xgc[j + 256] * 0.25f; cx[3] = xgc[j + 384] * 0.25f;
  }

  // enc L0 xg prefetch, depth 2 (named regs)
  const half_t* xbase = nullptr;
  f16x4 xqA = {}, xqB = {};
  if (!DEC) {
    xbase = xg0 + (size_t)b * NT * NG + (j << 2);
    xqA = *(const f16x4*)(xbase);
    xqB = *(const f16x4*)(xbase + NG);
  }

  __syncthreads();

  auto stepf = [&](int s, f16x4& xq) {
    // ---------- L0: t = s ----------
    if (s < NT) {
      f16x4 cur = xq;
      if (!DEC && s + 2 < NT)
        xq = *(const f16x4*)(xbase + (size_t)(s + 2) * NG);  // issue early

      float pa[4], pb[4];
      if (DEC) {
#pragma unroll
        for (int gi = 0; gi < 4; ++gi) pa[gi] = cx[gi];
      } else {
#pragma unroll
        for (int gi = 0; gi < 4; ++gi) pa[gi] = (float)cur[gi] * 0.25f;
      }
#pragma unroll
      for (int gi = 0; gi < 4; ++gi) pb[gi] = 0.f;

      const f16x8* hv8 = reinterpret_cast<const f16x8*>(&h0buf[(s + 1) & 1][kq][0]);
#pragma unroll
      for (int r8 = 0; r8 < 4; ++r8) {
        const f16x8 H = hv8[r8];
        const half2_t h0 = __builtin_shufflevector(H, H, 0, 1);
        const half2_t h1 = __builtin_shufflevector(H, H, 2, 3);
        const half2_t h2 = __builtin_shufflevector(H, H, 4, 5);
        const half2_t h3 = __builtin_shufflevector(H, H, 6, 7);
#pragma unroll
        for (int gi = 0; gi < 4; ++gi) {
          const f16x8 W = wh0[gi][r8];
          float sa = pa[gi], sb = pb[gi];
          sa = fdot2(__builtin_shufflevector(W, W, 0, 1), h0, sa);
          sb = fdot2(__builtin_shufflevector(W, W, 2, 3), h1, sb);
          sa = fdot2(__builtin_shufflevector(W, W, 4, 5), h2, sa);
          sb = fdot2(__builtin_shufflevector(W, W, 6, 7), h3, sb);
          pa[gi] = sa; pb[gi] = sb;
        }
      }
      const float a0 = qreduce(pa[0] + pb[0]);
      const float a1 = qreduce(pa[1] + pb[1]);
      const float a2 = qreduce(pa[2] + pb[2]);
      const float a3 = qreduce(pa[3] + pb[3]);

      const float ig = sigm(a0), fg = sigm(a1), gg = tanh_(a2), og = sigm(a3);
      c0 = fmaf(fg, c0, ig * gg);
      const float hh0 = og * tanh_(c0);
      if (kq == 0) h0buf[s & 1][j >> 5][j & 31] = (half_t)hh0;
    }

    // ---------- L1: t1 = s-1, concat [h1(s-2); h0(s-1)] ----------
    if (s >= 1) {
      const half_t* cA = (kq < 2) ? &h1buf[s & 1][2 * (kq & 1)][0]
                                  : &h0buf[(s + 1) & 1][2 * (kq & 1)][0];
      const f16x8* A8 = reinterpret_cast<const f16x8*>(cA);
      const f16x8* B8 = reinterpret_cast<const f16x8*>(cA + 48);  // next quarter

      float pc[4], pd[4];
#pragma unroll
      for (int gi = 0; gi < 4; ++gi) { pc[gi] = b1g[gi]; pd[gi] = 0.f; }

#pragma unroll
      for (int r8 = 0; r8 < 4; ++r8) {
        const f16x8 HA = A8[r8];
        const f16x8 HB = B8[r8];
        const half2_t a0p = __builtin_shufflevector(HA, HA, 0, 1);
        const half2_t a1p = __builtin_shufflevector(HA, HA, 2, 3);
        const half2_t a2p = __builtin_shufflevector(HA, HA, 4, 5);
        const half2_t a3p = __builtin_shufflevector(HA, HA, 6, 7);
        const half2_t b0p = __builtin_shufflevector(HB, HB, 0, 1);
        const half2_t b1p = __builtin_shufflevector(HB, HB, 2, 3);
        const half2_t b2p = __builtin_shufflevector(HB, HB, 4, 5);
        const half2_t b3p = __builtin_shufflevector(HB, HB, 6, 7);
#pragma unroll
        for (int gi = 0; gi < 4; ++gi) {
          const f16x8 WA = wc[gi][r8];
          const f16x8 WB = wc[gi][r8 + 4];
          float sc = pc[gi], sd = pd[gi];
          sc = fdot2(__builtin_shufflevector(WA, WA, 0, 1), a0p, sc);
          sd = fdot2(__builtin_shufflevector(WB, WB, 0, 1), b0p, sd);
          sc = fdot2(__builtin_shufflevector(WA, WA, 2, 3), a1p, sc);
          sd = fdot2(__builtin_shufflevector(WB, WB, 2, 3), b1p, sd);
          sc = fdot2(__builtin_shufflevector(WA, WA, 4, 5), a2p, sc);
          sd = fdot2(__builtin_shufflevector(WB, WB, 4, 5), b2p, sd);
          sc = fdot2(__builtin_shufflevector(WA, WA, 6, 7), a3p, sc);
          sd = fdot2(__builtin_shufflevector(WB, WB, 6, 7), b3p, sd);
          pc[gi] = sc; pd[gi] = sd;
        }
      }
      const float a0 = qreduce(pc[0] + pd[0]);
      const float a1 = qreduce(pc[1] + pd[1]);
      const float a2 = qreduce(pc[2] + pd[2]);
      const float a3 = qreduce(pc[3] + pd[3]);

      const float ig = sigm(a0), fg = sigm(a1), gg = tanh_(a2), og = sigm(a3);
      c1 = fmaf(fg, c1, ig * gg);
      const float hh1 = og * tanh_(c1);

      if (kq == 0) {
        h1buf[(s + 1) & 1][j >> 5][j & 31] = (half_t)hh1;
        if (DEC) seq_out[((size_t)b * NT + (s - 1)) * NH + j] = (half_t)hh1;
        else if (s == NT) hT_out[(size_t)b * NH + j] = hh1;
      }
    }
    __syncthreads();
  };

#pragma unroll 1
  for (int s = 0; s < NT; s += 2) {
    stepf(s, xqA);
    stepf(s + 1, xqB);
  }
  stepf(NT, xqA);  // drain: L1 computes t1 = NT-1 (L0 guarded off)
}

}  // namespace

extern "C" void kernel_launch(void* const* d_in, const int* in_sizes, int n_in,
                              void* d_out, int out_size, void* d_ws, size_t ws_size,
                              hipStream_t stream) {
  (void)in_sizes; (void)n_in; (void)out_size; (void)ws_size;

  const float* x     = (const float*)d_in[0];
  const float* e0Wih = (const float*)d_in[1];
  const float* e0Whh = (const float*)d_in[2];
  const float* e0bih = (const float*)d_in[3];
  const float* e0bhh = (const float*)d_in[4];
  const float* e1Wih = (const float*)d_in[5];
  const float* e1Whh = (const float*)d_in[6];
  const float* e1bih = (const float*)d_in[7];
  const float* e1bhh = (const float*)d_in[8];
  const float* d0Wih = (const float*)d_in[9];
  const float* d0Whh = (const float*)d_in[10];
  const float* d0bih = (const float*)d_in[11];
  const float* d0bhh = (const float*)d_in[12];
  const float* d1Wih = (const float*)d_in[13];
  const float* d1Whh = (const float*)d_in[14];
  const float* d1bih = (const float*)d_in[15];
  const float* d1bhh = (const float*)d_in[16];
  const float* Wout  = (const float*)d_in[17];
  const float* bout  = (const float*)d_in[18];
  float* out = (float*)d_out;

  // ws: 6 fp16 weight arrays | seqA fp16 [B*T,128] | xg0 fp16 [B*T,512] | hT f32
  half_t* whh0h = (half_t*)d_ws;
  half_t* whh1h = whh0h + 512 * 128;
  half_t* wih1h = whh1h + 512 * 128;
  half_t* whh2h = wih1h + 512 * 128;
  half_t* whh3h = whh2h + 512 * 128;
  half_t* wih3h = whh3h + 512 * 128;
  half_t* seqA  = wih3h + 512 * 128;
  half_t* xg0   = seqA + (size_t)NB * NT * NH;
  float*  hT    = (float*)(xg0 + (size_t)NB * NT * NG);

  cvt_kernel<<<64, 256, 0, stream>>>(e0Whh, whh0h, 512 * 128 / 4);
  cvt_kernel<<<64, 256, 0, stream>>>(e1Whh, whh1h, 512 * 128 / 4);
  cvt_kernel<<<64, 256, 0, stream>>>(e1Wih, wih1h, 512 * 128 / 4);
  cvt_kernel<<<64, 256, 0, stream>>>(d0Whh, whh2h, 512 * 128 / 4);
  cvt_kernel<<<64, 256, 0, stream>>>(d1Whh, whh3h, 512 * 128 / 4);
  cvt_kernel<<<64, 256, 0, stream>>>(d1Wih, wih3h, 512 * 128 / 4);

  const int M = NB * NT;  // 131072
  dim3 gX(M / 128, NG / 64), gP(M / 128, 1), blkG(256);
  dim3 gR(NB), blkR(512);

  // enc0 input GEMM: xg0 = x @ e0Wih^T + biases (unit-interleaved)
  xg_gemm<64, true, false><<<gX, blkG, 0, stream>>>(x, e0Wih, e0bih, e0bhh, xg0, nullptr, NG);

  // fused encoder (enc0 + enc1): xg0 -> hT
  rec_fused<false><<<gR, blkR, 0, stream>>>(xg0, nullptr, nullptr, nullptr, nullptr,
                                            whh0h, whh1h, wih1h, e1bih, e1bhh,
                                            nullptr, hT);

  // fused decoder (dec0 + dec1): hT -> seqA (dec1 h-seq)
  rec_fused<true><<<gR, blkR, 0, stream>>>(nullptr, hT, d0Wih, d0bih, d0bhh,
                                           whh2h, whh3h, wih3h, d1bih, d1bhh,
                                           seqA, nullptr);

  // projection: out[b][t][f] = seqA @ Wout^T + bout
  xg_gemm<128, false, true><<<gP, blkG, 0, stream>>>(seqA, Wout, bout, nullptr, nullptr, out, 64);
}